// Round 16
// baseline (302.264 us; speedup 1.0000x reference)
//
#include <hip/hip_runtime.h>
#include <hip/hip_bf16.h>

#define N_NODES 50000
#define N_EDGES 800000
#define MAXDEG 96
#define CSTRIDE 1

typedef __bf16 bf16x8 __attribute__((ext_vector_type(8)));
typedef float f32x4 __attribute__((ext_vector_type(4)));
typedef float f32x2 __attribute__((ext_vector_type(2)));
typedef unsigned short u16x8 __attribute__((ext_vector_type(8)));

__device__ __forceinline__ float loadF(const void* p, size_t i, bool isbf) {
    return isbf ? __bfloat162float(((const __hip_bfloat16*)p)[i]) : ((const float*)p)[i];
}
__device__ __forceinline__ float bfbits2f(unsigned short u) {
    return __uint_as_float(((unsigned)u) << 16);
}
__device__ __forceinline__ unsigned short f2bfbits(float f) {
    __hip_bfloat16 h = __float2bfloat16(f);
    return *(unsigned short*)&h;
}
__device__ __forceinline__ void acc8_fp8(float ex, uint2 r, float* acc) {
    f32x2 p0 = __builtin_amdgcn_cvt_pk_f32_fp8(r.x, false);
    f32x2 p1 = __builtin_amdgcn_cvt_pk_f32_fp8(r.x, true);
    f32x2 p2 = __builtin_amdgcn_cvt_pk_f32_fp8(r.y, false);
    f32x2 p3 = __builtin_amdgcn_cvt_pk_f32_fp8(r.y, true);
    acc[0] += ex * p0.x; acc[1] += ex * p0.y;
    acc[2] += ex * p1.x; acc[3] += ex * p1.y;
    acc[4] += ex * p2.x; acc[5] += ex * p2.y;
    acc[6] += ex * p3.x; acc[7] += ex * p3.y;
}

// ---------- small: dtype detect + weight conversion (14336 threads) ----------
__global__ __launch_bounds__(256)
void cvtw_k(const void* __restrict__ x, const void* __restrict__ W1,
            const void* __restrict__ W2, const void* __restrict__ Wo,
            unsigned short* __restrict__ W1f, unsigned short* __restrict__ W2f,
            unsigned short* __restrict__ Wof, int* __restrict__ flag) {
    __shared__ int s_flag;
    int t = threadIdx.x;
    if (t < 64) {
        const unsigned short* xw = (const unsigned short*)x;
        int cnt = 0;
        for (int i = t; i < 512; i += 64) {
            unsigned e = (xw[2 * i] >> 7) & 0xFFu;
            if (e >= 117u && e <= 134u) cnt++;
        }
        for (int off = 32; off; off >>= 1) cnt += __shfl_down(cnt, off, 64);
        if (t == 0) s_flag = (cnt >= 256) ? 1 : 0;
    }
    __syncthreads();
    bool bf = (s_flag != 0);
    int u = blockIdx.x * blockDim.x + t;
    if (u == 0) *flag = bf ? 1 : 0;
    if (u >= 14336) return;
    const void* W; unsigned short* dstp; int Nf, Npad, s, rem;
    if (u < 4096)        { W = W1; dstp = W1f; Nf = 256; Npad = 256; s = u / 1024; rem = u % 1024; }
    else if (u < 12288)  { u -= 4096;  W = W2; dstp = W2f; Nf = 256; Npad = 256; s = u / 1024; rem = u % 1024; }
    else                 { u -= 12288; W = Wo; dstp = Wof; Nf = 40;  Npad = 64;  s = u / 256;  rem = u % 256; }
    int n = rem >> 2, quad = rem & 3;
    unsigned short r[8];
    for (int j = 0; j < 8; ++j) {
        int k = s * 32 + quad * 8 + j;
        r[j] = (n < Nf) ? f2bfbits(loadF(W, (size_t)k * Nf + n, bf)) : (unsigned short)0;
    }
    int uo = (s * Npad + n) * 4 + quad;
    *(uint4*)(dstp + (size_t)uo * 8) = *(uint4*)r;
}

// ---------- full-width MFMA GEMM, swapped-operand layout; A = bf16 or f32 (in-reg cvt) ----------
template <bool AF32>
__device__ __forceinline__ bf16x8 load_a_frag(const void* A, size_t off) {
    if constexpr (!AF32) {
        return *(const bf16x8*)((const unsigned short*)A + off);
    } else {
        const float* p = (const float*)A + off;
        f32x4 v0 = *(const f32x4*)p;
        f32x4 v1 = *(const f32x4*)(p + 4);
        u16x8 u;
        u[0] = f2bfbits(v0[0]); u[1] = f2bfbits(v0[1]);
        u[2] = f2bfbits(v0[2]); u[3] = f2bfbits(v0[3]);
        u[4] = f2bfbits(v1[0]); u[5] = f2bfbits(v1[1]);
        u[6] = f2bfbits(v1[2]); u[7] = f2bfbits(v1[3]);
        return __builtin_bit_cast(bf16x8, u);
    }
}

// mfma(b, a): W-col -> C "row" slot (quad*4+reg), A-row -> C "col" slot (lane&15).
// Each lane holds 4 CONSECUTIVE cols of one row -> packed dword fp8 / 8B bf16 stores.
// DOSTAGE: stage the 64-row A panel in static LDS once per block (fragment-major
// [rowgrp][s][lane] 16B chunks). Staging row base is the BLOCK base bx*RB.
template <int K_, int AMODE, int WROWS, int WCOLS, int NTW, bool AF32, bool DOSTAGE>
__device__ __forceinline__
void gemm_attn_body(int bx, int t,
                    const void* __restrict__ A, const unsigned short* __restrict__ Wf,
                    void* __restrict__ Cout, const void* __restrict__ al,
                    const void* __restrict__ ar, const int* __restrict__ flag,
                    float* __restrict__ el, float* __restrict__ er, int M, int Nfull, int Npad) {
    constexpr int S = K_ / 32;
    constexpr int RB = WROWS * 32;
    int wave = t >> 6, lane = t & 63;
    int wrow = wave / WCOLS, wcol = wave % WCOLS;
    int m16 = lane & 15, quad = lane >> 4;
    int rbase = bx * RB + wrow * 32;
    int cbase = wcol * NTW * 16;

    int boff[NTW];
    for (int nt = 0; nt < NTW; ++nt) {
        int gc = cbase + nt * 16 + m16;
        boff[nt] = (gc * 4 + quad) * 8;
    }
    int bstep = Npad * 32;

    f32x4 acc[2][NTW] = {};

    if constexpr (DOSTAGE) {
        __shared__ unsigned char smem[RB * K_ * 2];   // 16 KB (K=128) / 32 KB (K=256)
        {
            int quad_t = t & 3, m16_t = (t >> 2) & 15, rowgrp_t = t >> 6;
            int gr = bx * RB + rowgrp_t * 16 + m16_t;          // block base
            int grc = (gr < M) ? gr : (M - 1);
            unsigned char* wp = smem + ((size_t)rowgrp_t * S * 64 + quad_t * 16 + m16_t) * 16;
            if constexpr (!AF32) {
                const uint4* grow = (const uint4*)((const unsigned short*)A + (size_t)grc * K_);
#pragma unroll
                for (int j = 0; j < S; ++j)
                    *(uint4*)(wp + (size_t)j * 64 * 16) = grow[j * 4 + quad_t];
            } else {
                const float* grow = (const float*)A + (size_t)grc * K_;
#pragma unroll
                for (int j = 0; j < S; ++j) {
                    const float* p = grow + (j * 4 + quad_t) * 8;
                    f32x4 v0 = *(const f32x4*)p;
                    f32x4 v1 = *(const f32x4*)(p + 4);
                    u16x8 u;
                    u[0] = f2bfbits(v0[0]); u[1] = f2bfbits(v0[1]);
                    u[2] = f2bfbits(v0[2]); u[3] = f2bfbits(v0[3]);
                    u[4] = f2bfbits(v1[0]); u[5] = f2bfbits(v1[1]);
                    u[6] = f2bfbits(v1[2]); u[7] = f2bfbits(v1[3]);
                    *(u16x8*)(wp + (size_t)j * 64 * 16) = u;
                }
            }
        }
        __syncthreads();

        bf16x8 b0[NTW], b1[NTW];
#pragma unroll
        for (int nt = 0; nt < NTW; ++nt) b0[nt] = *(const bf16x8*)(Wf + boff[nt]);
#pragma unroll
        for (int s = 0; s < S; ++s) {
            if (s + 1 < S) {
#pragma unroll
                for (int nt = 0; nt < NTW; ++nt)
                    b1[nt] = *(const bf16x8*)(Wf + boff[nt] + (size_t)(s + 1) * bstep);
            }
            bf16x8 a[2];
#pragma unroll
            for (int mt = 0; mt < 2; ++mt)
                a[mt] = *(const bf16x8*)(smem +
                    (((size_t)(wrow * 2 + mt) * S + s) * 64 + lane) * 16);
#pragma unroll
            for (int mt = 0; mt < 2; ++mt)
#pragma unroll
                for (int nt = 0; nt < NTW; ++nt)
                    acc[mt][nt] = __builtin_amdgcn_mfma_f32_16x16x32_bf16(
                        b0[nt], a[mt], acc[mt][nt], 0, 0, 0);
            if (s + 1 < S) {
#pragma unroll
                for (int nt = 0; nt < NTW; ++nt) b0[nt] = b1[nt];
            }
        }
    } else {
        int aoff[2];
        for (int mt = 0; mt < 2; ++mt) {
            int gr = rbase + mt * 16 + m16;
            int grc = (gr < M) ? gr : (M - 1);
            aoff[mt] = grc * K_ + quad * 8;
        }
        bf16x8 a0[2], a1[2], b0[NTW], b1[NTW];
#pragma unroll
        for (int mt = 0; mt < 2; ++mt) a0[mt] = load_a_frag<AF32>(A, aoff[mt]);
#pragma unroll
        for (int nt = 0; nt < NTW; ++nt) b0[nt] = *(const bf16x8*)(Wf + boff[nt]);
#pragma unroll
        for (int s = 0; s < S; ++s) {
            if (s + 1 < S) {
#pragma unroll
                for (int mt = 0; mt < 2; ++mt)
                    a1[mt] = load_a_frag<AF32>(A, aoff[mt] + (s + 1) * 32);
#pragma unroll
                for (int nt = 0; nt < NTW; ++nt)
                    b1[nt] = *(const bf16x8*)(Wf + boff[nt] + (size_t)(s + 1) * bstep);
            }
#pragma unroll
            for (int mt = 0; mt < 2; ++mt)
#pragma unroll
                for (int nt = 0; nt < NTW; ++nt)
                    acc[mt][nt] = __builtin_amdgcn_mfma_f32_16x16x32_bf16(
                        b0[nt], a0[mt], acc[mt][nt], 0, 0, 0);
            if (s + 1 < S) {
#pragma unroll
                for (int mt = 0; mt < 2; ++mt) a0[mt] = a1[mt];
#pragma unroll
                for (int nt = 0; nt < NTW; ++nt) b0[nt] = b1[nt];
            }
        }
    }

    // ---- C store: 4 consecutive cols per lane ----
    if (AMODE == 0) {
        unsigned char* C8 = (unsigned char*)Cout;
#pragma unroll
        for (int mt = 0; mt < 2; ++mt) {
            int gr = rbase + mt * 16 + m16;
            if (gr < M) {
#pragma unroll
                for (int nt = 0; nt < NTW; ++nt) {
                    int u = __builtin_amdgcn_cvt_pk_fp8_f32(acc[mt][nt][0], acc[mt][nt][1], 0, false);
                    u = __builtin_amdgcn_cvt_pk_fp8_f32(acc[mt][nt][2], acc[mt][nt][3], u, true);
                    *(int*)(C8 + (size_t)gr * 256 + cbase + nt * 16 + quad * 4) = u;
                }
            }
        }
    } else {
        __hip_bfloat16* C = (__hip_bfloat16*)Cout;
#pragma unroll
        for (int mt = 0; mt < 2; ++mt) {
            int gr = rbase + mt * 16 + m16;
            if (gr < M) {
#pragma unroll
                for (int nt = 0; nt < NTW; ++nt) {
                    ushort4 o;
                    o.x = f2bfbits(acc[mt][nt][0]);
                    o.y = f2bfbits(acc[mt][nt][1]);
                    o.z = f2bfbits(acc[mt][nt][2]);
                    o.w = f2bfbits(acc[mt][nt][3]);
                    *(ushort4*)((unsigned short*)C + (size_t)gr * Npad + cbase + nt * 16 + quad * 4) = o;
                }
            }
        }
    }

    // ---- el/er: reduce over cols; only 2 shfls (across quad) ----
    bool bf = (*flag != 0);
    if (AMODE == 0) {
#pragma unroll
        for (int h = 0; h < NTW / 2; ++h) {
            float alc2[2][4], arc2[2][4];
#pragma unroll
            for (int j = 0; j < 2; ++j)
#pragma unroll
                for (int r = 0; r < 4; ++r) {
                    int gc = cbase + (2 * h + j) * 16 + quad * 4 + r;
                    bool ok = gc < Nfull;
                    alc2[j][r] = ok ? loadF(al, gc, bf) : 0.f;
                    arc2[j][r] = ok ? loadF(ar, gc, bf) : 0.f;
                }
#pragma unroll
            for (int mt = 0; mt < 2; ++mt) {
                float pl = 0.f, pr = 0.f;
#pragma unroll
                for (int j = 0; j < 2; ++j)
#pragma unroll
                    for (int r = 0; r < 4; ++r) {
                        pl += acc[mt][2 * h + j][r] * alc2[j][r];
                        pr += acc[mt][2 * h + j][r] * arc2[j][r];
                    }
                pl += __shfl_xor(pl, 16, 64); pl += __shfl_xor(pl, 32, 64);
                pr += __shfl_xor(pr, 16, 64); pr += __shfl_xor(pr, 32, 64);
                int gr = rbase + mt * 16 + m16;
                if (quad == 0 && gr < M) {
                    int habs = wcol * (NTW / 2) + h;
                    el[gr * 8 + habs] = pl;
                    er[gr * 8 + habs] = pr;
                }
            }
        }
    } else {
        float pl[2] = {0.f, 0.f}, pr[2] = {0.f, 0.f};
#pragma unroll
        for (int nt = 0; nt < NTW; ++nt) {
            float alc4[4], arc4[4];
#pragma unroll
            for (int r = 0; r < 4; ++r) {
                int gc = cbase + nt * 16 + quad * 4 + r;
                bool ok = gc < Nfull;
                alc4[r] = ok ? loadF(al, gc, bf) : 0.f;
                arc4[r] = ok ? loadF(ar, gc, bf) : 0.f;
            }
#pragma unroll
            for (int mt = 0; mt < 2; ++mt)
#pragma unroll
                for (int r = 0; r < 4; ++r) {
                    pl[mt] += acc[mt][nt][r] * alc4[r];
                    pr[mt] += acc[mt][nt][r] * arc4[r];
                }
        }
#pragma unroll
        for (int mt = 0; mt < 2; ++mt) {
            float l = pl[mt], r = pr[mt];
            l += __shfl_xor(l, 16, 64); l += __shfl_xor(l, 32, 64);
            r += __shfl_xor(r, 16, 64); r += __shfl_xor(r, 32, 64);
            int gr = rbase + mt * 16 + m16;
            if (quad == 0 && gr < M) { el[gr] = l; er[gr] = r; }
        }
    }
}

template <int K_, int AMODE, int WROWS, int WCOLS, int NTW, bool DOSTAGE>
__global__ __launch_bounds__(256, 4)
void gemm_attn_k(const unsigned short* __restrict__ A, const unsigned short* __restrict__ Wf,
                 void* __restrict__ Cout, const void* __restrict__ al,
                 const void* __restrict__ ar, const int* __restrict__ flag,
                 float* __restrict__ el, float* __restrict__ er, int M, int Nfull, int Npad) {
    gemm_attn_body<K_, AMODE, WROWS, WCOLS, NTW, false, DOSTAGE>(blockIdx.x, threadIdx.x,
                                                                 A, Wf, Cout, al, ar, flag, el, er, M, Nfull, Npad);
}

// ---------- fused + STRIPED: padded-CSR histogram (MLP'd) + layer-1 GEMM (LDS-staged A) ----------
__global__ __launch_bounds__(256, 4)
void gemm1_hist_k(const void* __restrict__ xraw, const unsigned short* __restrict__ Wf,
                  void* __restrict__ Cout, const void* __restrict__ al,
                  const void* __restrict__ ar, const int* __restrict__ flag,
                  float* __restrict__ el, float* __restrict__ er, int M,
                  const int* __restrict__ src, const int* __restrict__ dst,
                  int* __restrict__ cursor, unsigned short* __restrict__ ecolp,
                  int E, int GB, int HB2) {
    int b = blockIdx.x, t = threadIdx.x;
    int T = gridDim.x;
    int gprev = (int)(((long long)b * GB) / T);
    int gnext = (int)(((long long)(b + 1) * GB) / T);
    if (gnext > gprev) {
        if (*flag != 0)
            gemm_attn_body<128, 0, 2, 2, 8, false, true>(gprev, t, xraw, Wf, Cout, al, ar, flag, el, er, M, 256, 256);
        else
            gemm_attn_body<128, 0, 2, 2, 8, true, true>(gprev, t, xraw, Wf, Cout, al, ar, flag, el, er, M, 256, 256);
    } else {
        int hb = b - gprev;                 // 0..HB2-1
        const int4* dst4 = (const int4*)dst;
        const int4* src4 = (const int4*)src;
        int nq = E >> 2;                    // int4 count (E % 4 == 0)
        int stride = HB2 * 256;
        for (int q = hb * 256 + t; q < nq; q += stride) {
            int4 d = dst4[q];
            int4 s = src4[q];
            int r0 = atomicAdd(&cursor[d.x * CSTRIDE], 1);
            int r1 = atomicAdd(&cursor[d.y * CSTRIDE], 1);
            int r2 = atomicAdd(&cursor[d.z * CSTRIDE], 1);
            int r3 = atomicAdd(&cursor[d.w * CSTRIDE], 1);
            if (r0 < MAXDEG) ecolp[(size_t)d.x * MAXDEG + r0] = (unsigned short)s.x;
            if (r1 < MAXDEG) ecolp[(size_t)d.y * MAXDEG + r1] = (unsigned short)s.y;
            if (r2 < MAXDEG) ecolp[(size_t)d.z * MAXDEG + r2] = (unsigned short)s.z;
            if (r3 < MAXDEG) ecolp[(size_t)d.w * MAXDEG + r3] = (unsigned short)s.w;
        }
    }
}

// ---------- single-pass half-wave aggregation (H=8, F=32), fp8 gather ----------
// 8-deep MLP + vectorized ushort4 index loads (ec is 8B-aligned; i%4==0).
__global__ __launch_bounds__(256)
void aggr1_k(const int* __restrict__ cursor, const unsigned short* __restrict__ ecolp,
             const float* __restrict__ el, const float* __restrict__ er,
             const unsigned char* __restrict__ Hp8, __hip_bfloat16* __restrict__ out, int N) {
    int t = threadIdx.x;
    int hw = t >> 5, l = t & 31;
    int n = blockIdx.x * 8 + hw;
    if (n >= N) return;
    int deg = cursor[n * CSTRIDE];
    if (deg > MAXDEG) deg = MAXDEG;
    const unsigned short* ec = ecolp + (size_t)n * MAXDEG;

    int hh = l >> 2;
    float er_hh = er[n * 8 + hh];
    float ss = 0.f;
    float acc[8] = {0.f, 0.f, 0.f, 0.f, 0.f, 0.f, 0.f, 0.f};

    int i = 0;
    for (; i + 8 <= deg; i += 8) {
        ushort4 ia = *(const ushort4*)(ec + i);
        ushort4 ib = *(const ushort4*)(ec + i + 4);
        int s0 = ia.x, s1 = ia.y, s2 = ia.z, s3 = ia.w;
        int s4 = ib.x, s5 = ib.y, s6 = ib.z, s7 = ib.w;
        uint2 r0 = *(const uint2*)(Hp8 + (size_t)s0 * 256 + l * 8);
        uint2 r1 = *(const uint2*)(Hp8 + (size_t)s1 * 256 + l * 8);
        uint2 r2 = *(const uint2*)(Hp8 + (size_t)s2 * 256 + l * 8);
        uint2 r3 = *(const uint2*)(Hp8 + (size_t)s3 * 256 + l * 8);
        uint2 r4 = *(const uint2*)(Hp8 + (size_t)s4 * 256 + l * 8);
        uint2 r5 = *(const uint2*)(Hp8 + (size_t)s5 * 256 + l * 8);
        uint2 r6 = *(const uint2*)(Hp8 + (size_t)s6 * 256 + l * 8);
        uint2 r7 = *(const uint2*)(Hp8 + (size_t)s7 * 256 + l * 8);
        float v0 = el[s0 * 8 + hh] + er_hh;
        float v1 = el[s1 * 8 + hh] + er_hh;
        float v2 = el[s2 * 8 + hh] + er_hh;
        float v3 = el[s3 * 8 + hh] + er_hh;
        float v4 = el[s4 * 8 + hh] + er_hh;
        float v5 = el[s5 * 8 + hh] + er_hh;
        float v6 = el[s6 * 8 + hh] + er_hh;
        float v7 = el[s7 * 8 + hh] + er_hh;
        v0 = (v0 >= 0.f) ? v0 : 0.2f * v0;
        v1 = (v1 >= 0.f) ? v1 : 0.2f * v1;
        v2 = (v2 >= 0.f) ? v2 : 0.2f * v2;
        v3 = (v3 >= 0.f) ? v3 : 0.2f * v3;
        v4 = (v4 >= 0.f) ? v4 : 0.2f * v4;
        v5 = (v5 >= 0.f) ? v5 : 0.2f * v5;
        v6 = (v6 >= 0.f) ? v6 : 0.2f * v6;
        v7 = (v7 >= 0.f) ? v7 : 0.2f * v7;
        float e0 = __expf(v0), e1 = __expf(v1), e2 = __expf(v2), e3 = __expf(v3);
        float e4 = __expf(v4), e5 = __expf(v5), e6 = __expf(v6), e7 = __expf(v7);
        ss += ((e0 + e1) + (e2 + e3)) + ((e4 + e5) + (e6 + e7));
        acc8_fp8(e0, r0, acc);
        acc8_fp8(e1, r1, acc);
        acc8_fp8(e2, r2, acc);
        acc8_fp8(e3, r3, acc);
        acc8_fp8(e4, r4, acc);
        acc8_fp8(e5, r5, acc);
        acc8_fp8(e6, r6, acc);
        acc8_fp8(e7, r7, acc);
    }
    for (; i + 4 <= deg; i += 4) {
        ushort4 ia = *(const ushort4*)(ec + i);
        int s0 = ia.x, s1 = ia.y, s2 = ia.z, s3 = ia.w;
        uint2 r0 = *(const uint2*)(Hp8 + (size_t)s0 * 256 + l * 8);
        uint2 r1 = *(const uint2*)(Hp8 + (size_t)s1 * 256 + l * 8);
        uint2 r2 = *(const uint2*)(Hp8 + (size_t)s2 * 256 + l * 8);
        uint2 r3 = *(const uint2*)(Hp8 + (size_t)s3 * 256 + l * 8);
        float v0 = el[s0 * 8 + hh] + er_hh;
        float v1 = el[s1 * 8 + hh] + er_hh;
        float v2 = el[s2 * 8 + hh] + er_hh;
        float v3 = el[s3 * 8 + hh] + er_hh;
        v0 = (v0 >= 0.f) ? v0 : 0.2f * v0;
        v1 = (v1 >= 0.f) ? v1 : 0.2f * v1;
        v2 = (v2 >= 0.f) ? v2 : 0.2f * v2;
        v3 = (v3 >= 0.f) ? v3 : 0.2f * v3;
        float e0 = __expf(v0), e1 = __expf(v1), e2 = __expf(v2), e3 = __expf(v3);
        ss += (e0 + e1) + (e2 + e3);
        acc8_fp8(e0, r0, acc);
        acc8_fp8(e1, r1, acc);
        acc8_fp8(e2, r2, acc);
        acc8_fp8(e3, r3, acc);
    }
    for (; i < deg; ++i) {
        int s0 = ec[i];
        uint2 r0 = *(const uint2*)(Hp8 + (size_t)s0 * 256 + l * 8);
        float v0 = el[s0 * 8 + hh] + er_hh;
        v0 = (v0 >= 0.f) ? v0 : 0.2f * v0;
        float e0 = __expf(v0);
        ss += e0;
        acc8_fp8(e0, r0, acc);
    }

    float inv = 1.f / (ss + 1e-16f);
    unsigned short o[8];
    for (int j = 0; j < 8; ++j) {
        float vv = acc[j] * inv;
        vv = (vv > 0.f) ? vv : expm1f(vv);   // ELU
        o[j] = f2bfbits(vv);
    }
    *(uint4*)((unsigned short*)out + (size_t)n * 256 + l * 8) = *(uint4*)o;
}

// ---------- output layer: 4 nodes / 256-thread block (1 wave per node) + log_softmax ----------
__global__ __launch_bounds__(256)
void aggr_out_k(const int* __restrict__ cursor, const unsigned short* __restrict__ ecolp,
                const float* __restrict__ elo, const float* __restrict__ ero,
                const unsigned short* __restrict__ Hp64, void* __restrict__ outp,
                const int* __restrict__ flag, int N) {
    int t = threadIdx.x;
    int n = blockIdx.x * 4 + (t >> 6);
    int l = t & 63;
    if (n >= N) return;
    int g = l >> 3, f = l & 7;
    int deg = cursor[n * CSTRIDE];
    if (deg > MAXDEG) deg = MAXDEG;
    const unsigned short* ec = ecolp + (size_t)n * MAXDEG;
    float ero_n = ero[n];
    float ss = 0.f;
    float acc[8] = {0.f, 0.f, 0.f, 0.f, 0.f, 0.f, 0.f, 0.f};
    for (int i = g; i < deg; i += 8) {
        int s = ec[i];
        float v = elo[s] + ero_n;
        v = (v >= 0.f) ? v : 0.2f * v;
        float ex = __expf(v);
        ss += ex;
        uint4 r = *(const uint4*)(Hp64 + (size_t)s * 64 + f * 8);
        unsigned short u[8];
        *(uint4*)u = r;
        for (int j = 0; j < 8; ++j) acc[j] += ex * bfbits2f(u[j]);
    }
    for (int off = 8; off <= 32; off <<= 1) {
        ss += __shfl_xor(ss, off, 64);
        for (int j = 0; j < 8; ++j) acc[j] += __shfl_xor(acc[j], off, 64);
    }
    float inv = 1.f / (ss + 1e-16f);
    float r8[8];
    float vmax = -1e30f;
    for (int j = 0; j < 8; ++j) {
        r8[j] = acc[j] * inv;
        if (f < 5) vmax = fmaxf(vmax, r8[j]);
    }
    for (int off = 1; off <= 4; off <<= 1) vmax = fmaxf(vmax, __shfl_xor(vmax, off, 64));
    float es = 0.f;
    if (f < 5)
        for (int j = 0; j < 8; ++j) es += __expf(r8[j] - vmax);
    for (int off = 1; off <= 4; off <<= 1) es += __shfl_xor(es, off, 64);
    float lse = vmax + logf(es);
    if (f < 5 && g == 0) {
        if (*flag) {
            unsigned short o[8];
            for (int j = 0; j < 8; ++j) o[j] = f2bfbits(r8[j] - lse);
            *(uint4*)((unsigned short*)outp + (size_t)n * 40 + f * 8) = *(uint4*)o;
        } else {
            float* fo = (float*)outp + (size_t)n * 40 + f * 8;
            for (int j = 0; j < 8; ++j) fo[j] = r8[j] - lse;
        }
    }
}

extern "C" void kernel_launch(void* const* d_in, const int* in_sizes, int n_in,
                              void* d_out, int out_size, void* d_ws, size_t ws_size,
                              hipStream_t stream) {
    const int N = N_NODES, E = N_EDGES;
    const void* x   = d_in[0];
    const int* src  = (const int*)d_in[1];
    const int* dst  = (const int*)d_in[2];
    const void* W1  = d_in[3];
    const void* al1 = d_in[4];
    const void* ar1 = d_in[5];
    const void* W2  = d_in[6];
    const void* al2 = d_in[7];
    const void* ar2 = d_in[8];
    const void* Wo  = d_in[9];
    const void* alo = d_in[10];
    const void* aro = d_in[11];

    // workspace (~52 MB)
    char* w = (char*)d_ws;
    auto alloc = [&](size_t bytes) { void* p = (void*)w; w += (bytes + 255) & ~(size_t)255; return p; };
    int* flag      = (int*)alloc(4);
    int* cursor    = (int*)alloc((size_t)N * CSTRIDE * 4);
    float* elo     = (float*)alloc((size_t)N * 4);
    float* ero     = (float*)alloc((size_t)N * 4);
    unsigned short* ecolp = (unsigned short*)alloc((size_t)N * MAXDEG * 2);
    float* el      = (float*)alloc((size_t)N * 8 * 4);
    float* er      = (float*)alloc((size_t)N * 8 * 4);
    unsigned short* W1f = (unsigned short*)alloc((size_t)128 * 256 * 2);
    unsigned short* W2f = (unsigned short*)alloc((size_t)256 * 256 * 2);
    unsigned short* Wof = (unsigned short*)alloc((size_t)256 * 64 * 2);
    // Hp region: fp8 N*256 B for layers 1/2; bf16 N*64*2 B for the output layer (aliased)
    unsigned char* Hp8 = (unsigned char*)alloc((size_t)N * 256);
    __hip_bfloat16* Hagg = (__hip_bfloat16*)alloc((size_t)N * 256 * 2);
    unsigned short* Hp64 = (unsigned short*)Hp8;  // alias: output-layer bf16 proj (Hp8 dead)

    int GB = (N + 63) / 64;      // full-width layer-GEMM blocks (64 rows x 256 cols)
    int OB = (N + 127) / 128;    // output-GEMM blocks (128 rows x 64 cols)
    int AB = (N + 7) / 8;
    int AOB = (N + 3) / 4;       // output-aggregation blocks (4 nodes each)
    int HB2 = 392;               // MLP'd histogram blocks (~8 edges/thread)
    int WVT = (14336 + 255) / 256;

    // 1: zero cursor (histogram base)
    hipMemsetAsync(cursor, 0, (size_t)N * CSTRIDE * 4, stream);
    // 2: dtype detect + weight conversion (tiny)
    cvtw_k<<<WVT, 256, 0, stream>>>(x, W1, W2, Wo, W1f, W2f, Wof, flag);
    // 3: striped padded-CSR histogram + layer-1 GEMM (LDS-staged A; 4 blocks/CU)
    gemm1_hist_k<<<HB2 + GB, 256, 0, stream>>>(
        x, W1f, Hp8, al1, ar1, flag, el, er, N, src, dst, cursor, ecolp, E, GB, HB2);
    // 4: layer-1 aggregation (fp8 gather, 8-deep MLP)
    aggr1_k<<<AB, 256, 0, stream>>>(cursor, ecolp, el, er, Hp8, Hagg, N);
    // 5: layer-2 GEMM (fp8 out, full-width, LDS-staged A; 4 blocks/CU)
    gemm_attn_k<256, 0, 2, 2, 8, true><<<GB, 256, 0, stream>>>(
        (const unsigned short*)Hagg, W2f, Hp8, al2, ar2, flag, el, er, N, 256, 256);
    // 6: layer-2 aggregation
    aggr1_k<<<AB, 256, 0, stream>>>(cursor, ecolp, el, er, Hp8, Hagg, N);
    // 7: output GEMM (bf16 out, stride 64; full-row el/er, no atomics; no staging)
    gemm_attn_k<256, 1, 4, 1, 4, false><<<OB, 256, 0, stream>>>(
        (const unsigned short*)Hagg, Wof, Hp64, alo, aro, flag, elo, ero, N, 40, 64);
    // 8: output aggregation + log_softmax (4 nodes/block)
    aggr_out_k<<<AOB, 256, 0, stream>>>(cursor, ecolp, elo, ero, Hp64, d_out, flag, N);
}

// Round 17
// 294.057 us; speedup vs baseline: 1.0279x; 1.0279x over previous
//
#include <hip/hip_runtime.h>
#include <hip/hip_bf16.h>

#define N_NODES 50000
#define N_EDGES 800000
#define MAXDEG 96
#define CSTRIDE 1

typedef __bf16 bf16x8 __attribute__((ext_vector_type(8)));
typedef float f32x4 __attribute__((ext_vector_type(4)));
typedef float f32x2 __attribute__((ext_vector_type(2)));
typedef unsigned short u16x8 __attribute__((ext_vector_type(8)));

__device__ __forceinline__ float loadF(const void* p, size_t i, bool isbf) {
    return isbf ? __bfloat162float(((const __hip_bfloat16*)p)[i]) : ((const float*)p)[i];
}
__device__ __forceinline__ float bfbits2f(unsigned short u) {
    return __uint_as_float(((unsigned)u) << 16);
}
__device__ __forceinline__ unsigned short f2bfbits(float f) {
    __hip_bfloat16 h = __float2bfloat16(f);
    return *(unsigned short*)&h;
}
__device__ __forceinline__ void acc8_fp8(float ex, uint2 r, float* acc) {
    f32x2 p0 = __builtin_amdgcn_cvt_pk_f32_fp8(r.x, false);
    f32x2 p1 = __builtin_amdgcn_cvt_pk_f32_fp8(r.x, true);
    f32x2 p2 = __builtin_amdgcn_cvt_pk_f32_fp8(r.y, false);
    f32x2 p3 = __builtin_amdgcn_cvt_pk_f32_fp8(r.y, true);
    acc[0] += ex * p0.x; acc[1] += ex * p0.y;
    acc[2] += ex * p1.x; acc[3] += ex * p1.y;
    acc[4] += ex * p2.x; acc[5] += ex * p2.y;
    acc[6] += ex * p3.x; acc[7] += ex * p3.y;
}

// ---------- small: dtype detect + weight conversion (14336 threads) ----------
__global__ __launch_bounds__(256)
void cvtw_k(const void* __restrict__ x, const void* __restrict__ W1,
            const void* __restrict__ W2, const void* __restrict__ Wo,
            unsigned short* __restrict__ W1f, unsigned short* __restrict__ W2f,
            unsigned short* __restrict__ Wof, int* __restrict__ flag) {
    __shared__ int s_flag;
    int t = threadIdx.x;
    if (t < 64) {
        const unsigned short* xw = (const unsigned short*)x;
        int cnt = 0;
        for (int i = t; i < 512; i += 64) {
            unsigned e = (xw[2 * i] >> 7) & 0xFFu;
            if (e >= 117u && e <= 134u) cnt++;
        }
        for (int off = 32; off; off >>= 1) cnt += __shfl_down(cnt, off, 64);
        if (t == 0) s_flag = (cnt >= 256) ? 1 : 0;
    }
    __syncthreads();
    bool bf = (s_flag != 0);
    int u = blockIdx.x * blockDim.x + t;
    if (u == 0) *flag = bf ? 1 : 0;
    if (u >= 14336) return;
    const void* W; unsigned short* dstp; int Nf, Npad, s, rem;
    if (u < 4096)        { W = W1; dstp = W1f; Nf = 256; Npad = 256; s = u / 1024; rem = u % 1024; }
    else if (u < 12288)  { u -= 4096;  W = W2; dstp = W2f; Nf = 256; Npad = 256; s = u / 1024; rem = u % 1024; }
    else                 { u -= 12288; W = Wo; dstp = Wof; Nf = 40;  Npad = 64;  s = u / 256;  rem = u % 256; }
    int n = rem >> 2, quad = rem & 3;
    unsigned short r[8];
    for (int j = 0; j < 8; ++j) {
        int k = s * 32 + quad * 8 + j;
        r[j] = (n < Nf) ? f2bfbits(loadF(W, (size_t)k * Nf + n, bf)) : (unsigned short)0;
    }
    int uo = (s * Npad + n) * 4 + quad;
    *(uint4*)(dstp + (size_t)uo * 8) = *(uint4*)r;
}

// ---------- full-width MFMA GEMM, swapped-operand layout; A = bf16 or f32 (in-reg cvt) ----------
template <bool AF32>
__device__ __forceinline__ bf16x8 load_a_frag(const void* A, size_t off) {
    if constexpr (!AF32) {
        return *(const bf16x8*)((const unsigned short*)A + off);
    } else {
        const float* p = (const float*)A + off;
        f32x4 v0 = *(const f32x4*)p;
        f32x4 v1 = *(const f32x4*)(p + 4);
        u16x8 u;
        u[0] = f2bfbits(v0[0]); u[1] = f2bfbits(v0[1]);
        u[2] = f2bfbits(v0[2]); u[3] = f2bfbits(v0[3]);
        u[4] = f2bfbits(v1[0]); u[5] = f2bfbits(v1[1]);
        u[6] = f2bfbits(v1[2]); u[7] = f2bfbits(v1[3]);
        return __builtin_bit_cast(bf16x8, u);
    }
}

// mfma(b, a): W-col -> C "row" slot (quad*4+reg), A-row -> C "col" slot (lane&15).
// Each lane holds 4 CONSECUTIVE cols of one row -> packed dword fp8 / 8B bf16 stores.
// DOSTAGE: stage the 64-row A panel in static LDS once per block (fragment-major
// [rowgrp][s][lane] 16B chunks). Staging row base is the BLOCK base bx*RB.
template <int K_, int AMODE, int WROWS, int WCOLS, int NTW, bool AF32, bool DOSTAGE>
__device__ __forceinline__
void gemm_attn_body(int bx, int t,
                    const void* __restrict__ A, const unsigned short* __restrict__ Wf,
                    void* __restrict__ Cout, const void* __restrict__ al,
                    const void* __restrict__ ar, const int* __restrict__ flag,
                    float* __restrict__ el, float* __restrict__ er, int M, int Nfull, int Npad) {
    constexpr int S = K_ / 32;
    constexpr int RB = WROWS * 32;
    int wave = t >> 6, lane = t & 63;
    int wrow = wave / WCOLS, wcol = wave % WCOLS;
    int m16 = lane & 15, quad = lane >> 4;
    int rbase = bx * RB + wrow * 32;
    int cbase = wcol * NTW * 16;

    int boff[NTW];
    for (int nt = 0; nt < NTW; ++nt) {
        int gc = cbase + nt * 16 + m16;
        boff[nt] = (gc * 4 + quad) * 8;
    }
    int bstep = Npad * 32;

    f32x4 acc[2][NTW] = {};

    if constexpr (DOSTAGE) {
        __shared__ unsigned char smem[RB * K_ * 2];   // 16 KB (K=128) / 32 KB (K=256)
        {
            int quad_t = t & 3, m16_t = (t >> 2) & 15, rowgrp_t = t >> 6;
            int gr = bx * RB + rowgrp_t * 16 + m16_t;          // block base
            int grc = (gr < M) ? gr : (M - 1);
            unsigned char* wp = smem + ((size_t)rowgrp_t * S * 64 + quad_t * 16 + m16_t) * 16;
            if constexpr (!AF32) {
                const uint4* grow = (const uint4*)((const unsigned short*)A + (size_t)grc * K_);
#pragma unroll
                for (int j = 0; j < S; ++j)
                    *(uint4*)(wp + (size_t)j * 64 * 16) = grow[j * 4 + quad_t];
            } else {
                const float* grow = (const float*)A + (size_t)grc * K_;
#pragma unroll
                for (int j = 0; j < S; ++j) {
                    const float* p = grow + (j * 4 + quad_t) * 8;
                    f32x4 v0 = *(const f32x4*)p;
                    f32x4 v1 = *(const f32x4*)(p + 4);
                    u16x8 u;
                    u[0] = f2bfbits(v0[0]); u[1] = f2bfbits(v0[1]);
                    u[2] = f2bfbits(v0[2]); u[3] = f2bfbits(v0[3]);
                    u[4] = f2bfbits(v1[0]); u[5] = f2bfbits(v1[1]);
                    u[6] = f2bfbits(v1[2]); u[7] = f2bfbits(v1[3]);
                    *(u16x8*)(wp + (size_t)j * 64 * 16) = u;
                }
            }
        }
        __syncthreads();

        bf16x8 b0[NTW], b1[NTW];
#pragma unroll
        for (int nt = 0; nt < NTW; ++nt) b0[nt] = *(const bf16x8*)(Wf + boff[nt]);
#pragma unroll
        for (int s = 0; s < S; ++s) {
            if (s + 1 < S) {
#pragma unroll
                for (int nt = 0; nt < NTW; ++nt)
                    b1[nt] = *(const bf16x8*)(Wf + boff[nt] + (size_t)(s + 1) * bstep);
            }
            bf16x8 a[2];
#pragma unroll
            for (int mt = 0; mt < 2; ++mt)
                a[mt] = *(const bf16x8*)(smem +
                    (((size_t)(wrow * 2 + mt) * S + s) * 64 + lane) * 16);
#pragma unroll
            for (int mt = 0; mt < 2; ++mt)
#pragma unroll
                for (int nt = 0; nt < NTW; ++nt)
                    acc[mt][nt] = __builtin_amdgcn_mfma_f32_16x16x32_bf16(
                        b0[nt], a[mt], acc[mt][nt], 0, 0, 0);
            if (s + 1 < S) {
#pragma unroll
                for (int nt = 0; nt < NTW; ++nt) b0[nt] = b1[nt];
            }
        }
    } else {
        int aoff[2];
        for (int mt = 0; mt < 2; ++mt) {
            int gr = rbase + mt * 16 + m16;
            int grc = (gr < M) ? gr : (M - 1);
            aoff[mt] = grc * K_ + quad * 8;
        }
        bf16x8 a0[2], a1[2], b0[NTW], b1[NTW];
#pragma unroll
        for (int mt = 0; mt < 2; ++mt) a0[mt] = load_a_frag<AF32>(A, aoff[mt]);
#pragma unroll
        for (int nt = 0; nt < NTW; ++nt) b0[nt] = *(const bf16x8*)(Wf + boff[nt]);
#pragma unroll
        for (int s = 0; s < S; ++s) {
            if (s + 1 < S) {
#pragma unroll
                for (int mt = 0; mt < 2; ++mt)
                    a1[mt] = load_a_frag<AF32>(A, aoff[mt] + (s + 1) * 32);
#pragma unroll
                for (int nt = 0; nt < NTW; ++nt)
                    b1[nt] = *(const bf16x8*)(Wf + boff[nt] + (size_t)(s + 1) * bstep);
            }
#pragma unroll
            for (int mt = 0; mt < 2; ++mt)
#pragma unroll
                for (int nt = 0; nt < NTW; ++nt)
                    acc[mt][nt] = __builtin_amdgcn_mfma_f32_16x16x32_bf16(
                        b0[nt], a0[mt], acc[mt][nt], 0, 0, 0);
            if (s + 1 < S) {
#pragma unroll
                for (int mt = 0; mt < 2; ++mt) a0[mt] = a1[mt];
#pragma unroll
                for (int nt = 0; nt < NTW; ++nt) b0[nt] = b1[nt];
            }
        }
    }

    // ---- C store: 4 consecutive cols per lane ----
    if (AMODE == 0) {
        unsigned char* C8 = (unsigned char*)Cout;
#pragma unroll
        for (int mt = 0; mt < 2; ++mt) {
            int gr = rbase + mt * 16 + m16;
            if (gr < M) {
#pragma unroll
                for (int nt = 0; nt < NTW; ++nt) {
                    int u = __builtin_amdgcn_cvt_pk_fp8_f32(acc[mt][nt][0], acc[mt][nt][1], 0, false);
                    u = __builtin_amdgcn_cvt_pk_fp8_f32(acc[mt][nt][2], acc[mt][nt][3], u, true);
                    *(int*)(C8 + (size_t)gr * 256 + cbase + nt * 16 + quad * 4) = u;
                }
            }
        }
    } else {
        __hip_bfloat16* C = (__hip_bfloat16*)Cout;
#pragma unroll
        for (int mt = 0; mt < 2; ++mt) {
            int gr = rbase + mt * 16 + m16;
            if (gr < M) {
#pragma unroll
                for (int nt = 0; nt < NTW; ++nt) {
                    ushort4 o;
                    o.x = f2bfbits(acc[mt][nt][0]);
                    o.y = f2bfbits(acc[mt][nt][1]);
                    o.z = f2bfbits(acc[mt][nt][2]);
                    o.w = f2bfbits(acc[mt][nt][3]);
                    *(ushort4*)((unsigned short*)C + (size_t)gr * Npad + cbase + nt * 16 + quad * 4) = o;
                }
            }
        }
    }

    // ---- el/er: reduce over cols; only 2 shfls (across quad) ----
    bool bf = (*flag != 0);
    if (AMODE == 0) {
#pragma unroll
        for (int h = 0; h < NTW / 2; ++h) {
            float alc2[2][4], arc2[2][4];
#pragma unroll
            for (int j = 0; j < 2; ++j)
#pragma unroll
                for (int r = 0; r < 4; ++r) {
                    int gc = cbase + (2 * h + j) * 16 + quad * 4 + r;
                    bool ok = gc < Nfull;
                    alc2[j][r] = ok ? loadF(al, gc, bf) : 0.f;
                    arc2[j][r] = ok ? loadF(ar, gc, bf) : 0.f;
                }
#pragma unroll
            for (int mt = 0; mt < 2; ++mt) {
                float pl = 0.f, pr = 0.f;
#pragma unroll
                for (int j = 0; j < 2; ++j)
#pragma unroll
                    for (int r = 0; r < 4; ++r) {
                        pl += acc[mt][2 * h + j][r] * alc2[j][r];
                        pr += acc[mt][2 * h + j][r] * arc2[j][r];
                    }
                pl += __shfl_xor(pl, 16, 64); pl += __shfl_xor(pl, 32, 64);
                pr += __shfl_xor(pr, 16, 64); pr += __shfl_xor(pr, 32, 64);
                int gr = rbase + mt * 16 + m16;
                if (quad == 0 && gr < M) {
                    int habs = wcol * (NTW / 2) + h;
                    el[gr * 8 + habs] = pl;
                    er[gr * 8 + habs] = pr;
                }
            }
        }
    } else {
        float pl[2] = {0.f, 0.f}, pr[2] = {0.f, 0.f};
#pragma unroll
        for (int nt = 0; nt < NTW; ++nt) {
            float alc4[4], arc4[4];
#pragma unroll
            for (int r = 0; r < 4; ++r) {
                int gc = cbase + nt * 16 + quad * 4 + r;
                bool ok = gc < Nfull;
                alc4[r] = ok ? loadF(al, gc, bf) : 0.f;
                arc4[r] = ok ? loadF(ar, gc, bf) : 0.f;
            }
#pragma unroll
            for (int mt = 0; mt < 2; ++mt)
#pragma unroll
                for (int r = 0; r < 4; ++r) {
                    pl[mt] += acc[mt][nt][r] * alc4[r];
                    pr[mt] += acc[mt][nt][r] * arc4[r];
                }
        }
#pragma unroll
        for (int mt = 0; mt < 2; ++mt) {
            float l = pl[mt], r = pr[mt];
            l += __shfl_xor(l, 16, 64); l += __shfl_xor(l, 32, 64);
            r += __shfl_xor(r, 16, 64); r += __shfl_xor(r, 32, 64);
            int gr = rbase + mt * 16 + m16;
            if (quad == 0 && gr < M) { el[gr] = l; er[gr] = r; }
        }
    }
}

template <int K_, int AMODE, int WROWS, int WCOLS, int NTW, bool DOSTAGE>
__global__ __launch_bounds__(256, 2)
void gemm_attn_k(const unsigned short* __restrict__ A, const unsigned short* __restrict__ Wf,
                 void* __restrict__ Cout, const void* __restrict__ al,
                 const void* __restrict__ ar, const int* __restrict__ flag,
                 float* __restrict__ el, float* __restrict__ er, int M, int Nfull, int Npad) {
    gemm_attn_body<K_, AMODE, WROWS, WCOLS, NTW, false, DOSTAGE>(blockIdx.x, threadIdx.x,
                                                                 A, Wf, Cout, al, ar, flag, el, er, M, Nfull, Npad);
}

// ---------- fused + STRIPED: padded-CSR histogram (MLP'd) + layer-1 GEMM (LDS-staged A) ----------
__global__ __launch_bounds__(256, 2)
void gemm1_hist_k(const void* __restrict__ xraw, const unsigned short* __restrict__ Wf,
                  void* __restrict__ Cout, const void* __restrict__ al,
                  const void* __restrict__ ar, const int* __restrict__ flag,
                  float* __restrict__ el, float* __restrict__ er, int M,
                  const int* __restrict__ src, const int* __restrict__ dst,
                  int* __restrict__ cursor, unsigned short* __restrict__ ecolp,
                  int E, int GB, int HB2) {
    int b = blockIdx.x, t = threadIdx.x;
    int T = gridDim.x;
    int gprev = (int)(((long long)b * GB) / T);
    int gnext = (int)(((long long)(b + 1) * GB) / T);
    if (gnext > gprev) {
        if (*flag != 0)
            gemm_attn_body<128, 0, 2, 2, 8, false, true>(gprev, t, xraw, Wf, Cout, al, ar, flag, el, er, M, 256, 256);
        else
            gemm_attn_body<128, 0, 2, 2, 8, true, true>(gprev, t, xraw, Wf, Cout, al, ar, flag, el, er, M, 256, 256);
    } else {
        int hb = b - gprev;                 // 0..HB2-1
        const int4* dst4 = (const int4*)dst;
        const int4* src4 = (const int4*)src;
        int nq = E >> 2;                    // int4 count (E % 4 == 0)
        int stride = HB2 * 256;
        for (int q = hb * 256 + t; q < nq; q += stride) {
            int4 d = dst4[q];
            int4 s = src4[q];
            int r0 = atomicAdd(&cursor[d.x * CSTRIDE], 1);
            int r1 = atomicAdd(&cursor[d.y * CSTRIDE], 1);
            int r2 = atomicAdd(&cursor[d.z * CSTRIDE], 1);
            int r3 = atomicAdd(&cursor[d.w * CSTRIDE], 1);
            if (r0 < MAXDEG) ecolp[(size_t)d.x * MAXDEG + r0] = (unsigned short)s.x;
            if (r1 < MAXDEG) ecolp[(size_t)d.y * MAXDEG + r1] = (unsigned short)s.y;
            if (r2 < MAXDEG) ecolp[(size_t)d.z * MAXDEG + r2] = (unsigned short)s.z;
            if (r3 < MAXDEG) ecolp[(size_t)d.w * MAXDEG + r3] = (unsigned short)s.w;
        }
    }
}

// ---------- single-pass half-wave aggregation (H=8, F=32), fp8 gather ----------
// 8-deep MLP + vectorized ushort4 index loads (ec is 8B-aligned; i%4==0).
__global__ __launch_bounds__(256)
void aggr1_k(const int* __restrict__ cursor, const unsigned short* __restrict__ ecolp,
             const float* __restrict__ el, const float* __restrict__ er,
             const unsigned char* __restrict__ Hp8, __hip_bfloat16* __restrict__ out, int N) {
    int t = threadIdx.x;
    int hw = t >> 5, l = t & 31;
    int n = blockIdx.x * 8 + hw;
    if (n >= N) return;
    int deg = cursor[n * CSTRIDE];
    if (deg > MAXDEG) deg = MAXDEG;
    const unsigned short* ec = ecolp + (size_t)n * MAXDEG;

    int hh = l >> 2;
    float er_hh = er[n * 8 + hh];
    float ss = 0.f;
    float acc[8] = {0.f, 0.f, 0.f, 0.f, 0.f, 0.f, 0.f, 0.f};

    int i = 0;
    for (; i + 8 <= deg; i += 8) {
        ushort4 ia = *(const ushort4*)(ec + i);
        ushort4 ib = *(const ushort4*)(ec + i + 4);
        int s0 = ia.x, s1 = ia.y, s2 = ia.z, s3 = ia.w;
        int s4 = ib.x, s5 = ib.y, s6 = ib.z, s7 = ib.w;
        uint2 r0 = *(const uint2*)(Hp8 + (size_t)s0 * 256 + l * 8);
        uint2 r1 = *(const uint2*)(Hp8 + (size_t)s1 * 256 + l * 8);
        uint2 r2 = *(const uint2*)(Hp8 + (size_t)s2 * 256 + l * 8);
        uint2 r3 = *(const uint2*)(Hp8 + (size_t)s3 * 256 + l * 8);
        uint2 r4 = *(const uint2*)(Hp8 + (size_t)s4 * 256 + l * 8);
        uint2 r5 = *(const uint2*)(Hp8 + (size_t)s5 * 256 + l * 8);
        uint2 r6 = *(const uint2*)(Hp8 + (size_t)s6 * 256 + l * 8);
        uint2 r7 = *(const uint2*)(Hp8 + (size_t)s7 * 256 + l * 8);
        float v0 = el[s0 * 8 + hh] + er_hh;
        float v1 = el[s1 * 8 + hh] + er_hh;
        float v2 = el[s2 * 8 + hh] + er_hh;
        float v3 = el[s3 * 8 + hh] + er_hh;
        float v4 = el[s4 * 8 + hh] + er_hh;
        float v5 = el[s5 * 8 + hh] + er_hh;
        float v6 = el[s6 * 8 + hh] + er_hh;
        float v7 = el[s7 * 8 + hh] + er_hh;
        v0 = (v0 >= 0.f) ? v0 : 0.2f * v0;
        v1 = (v1 >= 0.f) ? v1 : 0.2f * v1;
        v2 = (v2 >= 0.f) ? v2 : 0.2f * v2;
        v3 = (v3 >= 0.f) ? v3 : 0.2f * v3;
        v4 = (v4 >= 0.f) ? v4 : 0.2f * v4;
        v5 = (v5 >= 0.f) ? v5 : 0.2f * v5;
        v6 = (v6 >= 0.f) ? v6 : 0.2f * v6;
        v7 = (v7 >= 0.f) ? v7 : 0.2f * v7;
        float e0 = __expf(v0), e1 = __expf(v1), e2 = __expf(v2), e3 = __expf(v3);
        float e4 = __expf(v4), e5 = __expf(v5), e6 = __expf(v6), e7 = __expf(v7);
        ss += ((e0 + e1) + (e2 + e3)) + ((e4 + e5) + (e6 + e7));
        acc8_fp8(e0, r0, acc);
        acc8_fp8(e1, r1, acc);
        acc8_fp8(e2, r2, acc);
        acc8_fp8(e3, r3, acc);
        acc8_fp8(e4, r4, acc);
        acc8_fp8(e5, r5, acc);
        acc8_fp8(e6, r6, acc);
        acc8_fp8(e7, r7, acc);
    }
    for (; i + 4 <= deg; i += 4) {
        ushort4 ia = *(const ushort4*)(ec + i);
        int s0 = ia.x, s1 = ia.y, s2 = ia.z, s3 = ia.w;
        uint2 r0 = *(const uint2*)(Hp8 + (size_t)s0 * 256 + l * 8);
        uint2 r1 = *(const uint2*)(Hp8 + (size_t)s1 * 256 + l * 8);
        uint2 r2 = *(const uint2*)(Hp8 + (size_t)s2 * 256 + l * 8);
        uint2 r3 = *(const uint2*)(Hp8 + (size_t)s3 * 256 + l * 8);
        float v0 = el[s0 * 8 + hh] + er_hh;
        float v1 = el[s1 * 8 + hh] + er_hh;
        float v2 = el[s2 * 8 + hh] + er_hh;
        float v3 = el[s3 * 8 + hh] + er_hh;
        v0 = (v0 >= 0.f) ? v0 : 0.2f * v0;
        v1 = (v1 >= 0.f) ? v1 : 0.2f * v1;
        v2 = (v2 >= 0.f) ? v2 : 0.2f * v2;
        v3 = (v3 >= 0.f) ? v3 : 0.2f * v3;
        float e0 = __expf(v0), e1 = __expf(v1), e2 = __expf(v2), e3 = __expf(v3);
        ss += (e0 + e1) + (e2 + e3);
        acc8_fp8(e0, r0, acc);
        acc8_fp8(e1, r1, acc);
        acc8_fp8(e2, r2, acc);
        acc8_fp8(e3, r3, acc);
    }
    for (; i < deg; ++i) {
        int s0 = ec[i];
        uint2 r0 = *(const uint2*)(Hp8 + (size_t)s0 * 256 + l * 8);
        float v0 = el[s0 * 8 + hh] + er_hh;
        v0 = (v0 >= 0.f) ? v0 : 0.2f * v0;
        float e0 = __expf(v0);
        ss += e0;
        acc8_fp8(e0, r0, acc);
    }

    float inv = 1.f / (ss + 1e-16f);
    unsigned short o[8];
    for (int j = 0; j < 8; ++j) {
        float vv = acc[j] * inv;
        vv = (vv > 0.f) ? vv : expm1f(vv);   // ELU
        o[j] = f2bfbits(vv);
    }
    *(uint4*)((unsigned short*)out + (size_t)n * 256 + l * 8) = *(uint4*)o;
}

// ---------- output layer: 4 nodes / 256-thread block (1 wave per node) + log_softmax ----------
__global__ __launch_bounds__(256)
void aggr_out_k(const int* __restrict__ cursor, const unsigned short* __restrict__ ecolp,
                const float* __restrict__ elo, const float* __restrict__ ero,
                const unsigned short* __restrict__ Hp64, void* __restrict__ outp,
                const int* __restrict__ flag, int N) {
    int t = threadIdx.x;
    int n = blockIdx.x * 4 + (t >> 6);
    int l = t & 63;
    if (n >= N) return;
    int g = l >> 3, f = l & 7;
    int deg = cursor[n * CSTRIDE];
    if (deg > MAXDEG) deg = MAXDEG;
    const unsigned short* ec = ecolp + (size_t)n * MAXDEG;
    float ero_n = ero[n];
    float ss = 0.f;
    float acc[8] = {0.f, 0.f, 0.f, 0.f, 0.f, 0.f, 0.f, 0.f};
    for (int i = g; i < deg; i += 8) {
        int s = ec[i];
        float v = elo[s] + ero_n;
        v = (v >= 0.f) ? v : 0.2f * v;
        float ex = __expf(v);
        ss += ex;
        uint4 r = *(const uint4*)(Hp64 + (size_t)s * 64 + f * 8);
        unsigned short u[8];
        *(uint4*)u = r;
        for (int j = 0; j < 8; ++j) acc[j] += ex * bfbits2f(u[j]);
    }
    for (int off = 8; off <= 32; off <<= 1) {
        ss += __shfl_xor(ss, off, 64);
        for (int j = 0; j < 8; ++j) acc[j] += __shfl_xor(acc[j], off, 64);
    }
    float inv = 1.f / (ss + 1e-16f);
    float r8[8];
    float vmax = -1e30f;
    for (int j = 0; j < 8; ++j) {
        r8[j] = acc[j] * inv;
        if (f < 5) vmax = fmaxf(vmax, r8[j]);
    }
    for (int off = 1; off <= 4; off <<= 1) vmax = fmaxf(vmax, __shfl_xor(vmax, off, 64));
    float es = 0.f;
    if (f < 5)
        for (int j = 0; j < 8; ++j) es += __expf(r8[j] - vmax);
    for (int off = 1; off <= 4; off <<= 1) es += __shfl_xor(es, off, 64);
    float lse = vmax + logf(es);
    if (f < 5 && g == 0) {
        if (*flag) {
            unsigned short o[8];
            for (int j = 0; j < 8; ++j) o[j] = f2bfbits(r8[j] - lse);
            *(uint4*)((unsigned short*)outp + (size_t)n * 40 + f * 8) = *(uint4*)o;
        } else {
            float* fo = (float*)outp + (size_t)n * 40 + f * 8;
            for (int j = 0; j < 8; ++j) fo[j] = r8[j] - lse;
        }
    }
}

extern "C" void kernel_launch(void* const* d_in, const int* in_sizes, int n_in,
                              void* d_out, int out_size, void* d_ws, size_t ws_size,
                              hipStream_t stream) {
    const int N = N_NODES, E = N_EDGES;
    const void* x   = d_in[0];
    const int* src  = (const int*)d_in[1];
    const int* dst  = (const int*)d_in[2];
    const void* W1  = d_in[3];
    const void* al1 = d_in[4];
    const void* ar1 = d_in[5];
    const void* W2  = d_in[6];
    const void* al2 = d_in[7];
    const void* ar2 = d_in[8];
    const void* Wo  = d_in[9];
    const void* alo = d_in[10];
    const void* aro = d_in[11];

    // workspace (~52 MB)
    char* w = (char*)d_ws;
    auto alloc = [&](size_t bytes) { void* p = (void*)w; w += (bytes + 255) & ~(size_t)255; return p; };
    int* flag      = (int*)alloc(4);
    int* cursor    = (int*)alloc((size_t)N * CSTRIDE * 4);
    float* elo     = (float*)alloc((size_t)N * 4);
    float* ero     = (float*)alloc((size_t)N * 4);
    unsigned short* ecolp = (unsigned short*)alloc((size_t)N * MAXDEG * 2);
    float* el      = (float*)alloc((size_t)N * 8 * 4);
    float* er      = (float*)alloc((size_t)N * 8 * 4);
    unsigned short* W1f = (unsigned short*)alloc((size_t)128 * 256 * 2);
    unsigned short* W2f = (unsigned short*)alloc((size_t)256 * 256 * 2);
    unsigned short* Wof = (unsigned short*)alloc((size_t)256 * 64 * 2);
    // Hp region: fp8 N*256 B for layers 1/2; bf16 N*64*2 B for the output layer (aliased)
    unsigned char* Hp8 = (unsigned char*)alloc((size_t)N * 256);
    __hip_bfloat16* Hagg = (__hip_bfloat16*)alloc((size_t)N * 256 * 2);
    unsigned short* Hp64 = (unsigned short*)Hp8;  // alias: output-layer bf16 proj (Hp8 dead)

    int GB = (N + 63) / 64;      // full-width layer-GEMM blocks (64 rows x 256 cols)
    int OB = (N + 127) / 128;    // output-GEMM blocks (128 rows x 64 cols)
    int AB = (N + 7) / 8;
    int AOB = (N + 3) / 4;       // output-aggregation blocks (4 nodes each)
    int HB2 = 392;               // MLP'd histogram blocks (~8 edges/thread)
    int WVT = (14336 + 255) / 256;

    // 1: zero cursor (histogram base)
    hipMemsetAsync(cursor, 0, (size_t)N * CSTRIDE * 4, stream);
    // 2: dtype detect + weight conversion (tiny)
    cvtw_k<<<WVT, 256, 0, stream>>>(x, W1, W2, Wo, W1f, W2f, Wof, flag);
    // 3: striped padded-CSR histogram + layer-1 GEMM (LDS-staged A; 2 blocks/CU — measured best)
    gemm1_hist_k<<<HB2 + GB, 256, 0, stream>>>(
        x, W1f, Hp8, al1, ar1, flag, el, er, N, src, dst, cursor, ecolp, E, GB, HB2);
    // 4: layer-1 aggregation (fp8 gather, 8-deep MLP)
    aggr1_k<<<AB, 256, 0, stream>>>(cursor, ecolp, el, er, Hp8, Hagg, N);
    // 5: layer-2 GEMM (fp8 out, full-width, LDS-staged A: A fetched once)
    gemm_attn_k<256, 0, 2, 2, 8, true><<<GB, 256, 0, stream>>>(
        (const unsigned short*)Hagg, W2f, Hp8, al2, ar2, flag, el, er, N, 256, 256);
    // 6: layer-2 aggregation
    aggr1_k<<<AB, 256, 0, stream>>>(cursor, ecolp, el, er, Hp8, Hagg, N);
    // 7: output GEMM (bf16 out, stride 64; full-row el/er, no atomics; no staging)
    gemm_attn_k<256, 1, 4, 1, 4, false><<<OB, 256, 0, stream>>>(
        (const unsigned short*)Hagg, Wof, Hp64, alo, aro, flag, elo, ero, N, 40, 64);
    // 8: output aggregation + log_softmax (4 nodes/block)
    aggr_out_k<<<AOB, 256, 0, stream>>>(cursor, ecolp, elo, ero, Hp64, d_out, flag, N);
}